// Round 2
// baseline (878.869 us; speedup 1.0000x reference)
//
#include <hip/hip_runtime.h>

// Problem constants
constexpr int K    = 512;                 // codebook size
constexpr int CDIM = 64;                  // vector dim
constexpr int NVEC = 8 * 16 * 64 * 64;    // 524288 vectors
constexpr long long NELEM = (long long)NVEC * CDIM; // 33554432

// ws layout (bytes):
//   0    : double sse
//   8    : pad
//   16   : int    counts[512]   (ends 2064)
//   2064 : float  S2[512]       (ends 4112)
//   4112 : int    idx[NVEC]     (2 MB)
constexpr size_t OFF_SSE    = 0;
constexpr size_t OFF_COUNTS = 16;
constexpr size_t OFF_S2     = 16 + 4 * (size_t)K;
constexpr size_t OFF_IDX    = OFF_S2 + 4 * (size_t)K;

// ---------------------------------------------------------------------------
// numpy pairwise_sum emulation for exactly 64 fp32 values:
//   r[j] = v[j]; r[j] += v[8+j] ... r[j] += v[56+j];
//   res = ((r0+r1)+(r2+r3)) + ((r4+r5)+(r6+r7))
// v[] must already hold the individually-rounded squares.

// S2[k] = np.sum(cb[k]*cb[k]) with numpy pairwise semantics.
__global__ void k_prep(const float* __restrict__ cb, float* __restrict__ S2)
{
#pragma clang fp contract(off)
    int k = threadIdx.x;  // 512 threads, 1 block
    const float* e = cb + (k << 6);
    float sq[CDIM];
    #pragma unroll
    for (int c = 0; c < CDIM; ++c) {
        float v = e[c];
        sq[c] = v * v;                     // rounded square, NO fma
    }
    float r[8];
    #pragma unroll
    for (int j = 0; j < 8; ++j) r[j] = sq[j];
    #pragma unroll
    for (int i = 8; i < CDIM; i += 8)
        #pragma unroll
        for (int j = 0; j < 8; ++j) r[j] += sq[i + j];
    S2[k] = ((r[0] + r[1]) + (r[2] + r[3])) + ((r[4] + r[5]) + (r[6] + r[7]));
}

// ---------------------------------------------------------------------------
// Bit-exact numpy-fp32 emulation of
//   D[n,k] = (S1[n] - 2*G[n,k]) + S2[k],  G = sequential-fma dot (BLAS order),
//   idx[n] = argmin_k D (first minimum).
__global__ __launch_bounds__(256)
void k_scores(const float* __restrict__ x, const float* __restrict__ cb,
              const float* __restrict__ S2g, int* __restrict__ idx)
{
#pragma clang fp contract(off)
    const int n  = blockIdx.x * 256 + threadIdx.x;
    const int bt = n >> 12;           // (b*16+t)
    const int hw = n & 4095;          // h*64+w
    const float* xv = x + ((size_t)bt << 18) + (size_t)hw;

    float f[CDIM];
    #pragma unroll
    for (int c = 0; c < CDIM; ++c) f[c] = xv[(size_t)c << 12];

    // S1 = np pairwise sum of f*f (squares rounded first)
    float r[8];
    #pragma unroll
    for (int j = 0; j < 8; ++j) r[j] = f[j] * f[j];
    #pragma unroll
    for (int i = 8; i < CDIM; i += 8)
        #pragma unroll
        for (int j = 0; j < 8; ++j) r[j] += f[i + j] * f[i + j];
    const float S1 = ((r[0] + r[1]) + (r[2] + r[3])) + ((r[4] + r[5]) + (r[6] + r[7]));

    float best  = 3.4e38f;
    int   bestk = 0;

    for (int k = 0; k < K; k += 4) {
        const float4* e0 = (const float4*)(cb + ((k + 0) << 6));
        const float4* e1 = (const float4*)(cb + ((k + 1) << 6));
        const float4* e2 = (const float4*)(cb + ((k + 2) << 6));
        const float4* e3 = (const float4*)(cb + ((k + 3) << 6));
        float g0 = 0.f, g1 = 0.f, g2 = 0.f, g3 = 0.f;
        #pragma unroll
        for (int c4 = 0; c4 < 16; ++c4) {
            const int c = c4 * 4;
            float4 a = e0[c4];
            g0 = fmaf(f[c + 0], a.x, g0); g0 = fmaf(f[c + 1], a.y, g0);
            g0 = fmaf(f[c + 2], a.z, g0); g0 = fmaf(f[c + 3], a.w, g0);
            float4 b = e1[c4];
            g1 = fmaf(f[c + 0], b.x, g1); g1 = fmaf(f[c + 1], b.y, g1);
            g1 = fmaf(f[c + 2], b.z, g1); g1 = fmaf(f[c + 3], b.w, g1);
            float4 cc = e2[c4];
            g2 = fmaf(f[c + 0], cc.x, g2); g2 = fmaf(f[c + 1], cc.y, g2);
            g2 = fmaf(f[c + 2], cc.z, g2); g2 = fmaf(f[c + 3], cc.w, g2);
            float4 d = e3[c4];
            g3 = fmaf(f[c + 0], d.x, g3); g3 = fmaf(f[c + 1], d.y, g3);
            g3 = fmaf(f[c + 2], d.z, g3); g3 = fmaf(f[c + 3], d.w, g3);
        }
        // D = (S1 - 2*G) + S2   (2*G exact; adds round at magnitude ~64,
        // exactly like numpy's broadcast expression)
        const float d0 = (S1 - 2.f * g0) + S2g[k + 0];
        const float d1 = (S1 - 2.f * g1) + S2g[k + 1];
        const float d2 = (S1 - 2.f * g2) + S2g[k + 2];
        const float d3 = (S1 - 2.f * g3) + S2g[k + 3];
        // first-minimum selection, ascending k
        if (d0 < best) { best = d0; bestk = k + 0; }
        if (d1 < best) { best = d1; bestk = k + 1; }
        if (d2 < best) { best = d2; bestk = k + 2; }
        if (d3 < best) { best = d3; bestk = k + 3; }
    }

    idx[n] = bestk;
}

// ---------------------------------------------------------------------------
// Outputs: gather quantized, write indices-as-float, fp64 SSE, histogram.
__global__ __launch_bounds__(256)
void k_out(const float* __restrict__ x, const float* __restrict__ cb,
           const int* __restrict__ idx, float* __restrict__ outq,
           float* __restrict__ outidx, double* __restrict__ sse_g,
           int* __restrict__ counts)
{
    __shared__ int    hist[K];
    __shared__ double wsum[4];
    const int tid = threadIdx.x;
    for (int i = tid; i < K; i += 256) hist[i] = 0;
    __syncthreads();

    const int n  = blockIdx.x * 256 + tid;
    const int bt = n >> 12;
    const int hw = n & 4095;
    const size_t base = ((size_t)bt << 18) + (size_t)hw;
    const int k = idx[n];
    atomicAdd(&hist[k], 1);
    outidx[n] = (float)k;

    const float4* e4 = (const float4*)(cb + (k << 6));
    double acc = 0.0;
    #pragma unroll
    for (int c4 = 0; c4 < 16; ++c4) {
        float4 e = e4[c4];
        size_t o0 = base + ((size_t)(c4 * 4 + 0) << 12);
        size_t o1 = base + ((size_t)(c4 * 4 + 1) << 12);
        size_t o2 = base + ((size_t)(c4 * 4 + 2) << 12);
        size_t o3 = base + ((size_t)(c4 * 4 + 3) << 12);
        float d0 = e.x - x[o0]; outq[o0] = e.x;
        float d1 = e.y - x[o1]; outq[o1] = e.y;
        float d2 = e.z - x[o2]; outq[o2] = e.z;
        float d3 = e.w - x[o3]; outq[o3] = e.w;
        acc += (double)d0 * d0 + (double)d1 * d1 + (double)d2 * d2 + (double)d3 * d3;
    }

    double v = acc;
    #pragma unroll
    for (int off = 32; off; off >>= 1) v += __shfl_down(v, off, 64);
    if ((tid & 63) == 0) wsum[tid >> 6] = v;
    __syncthreads();
    if (tid == 0) atomicAdd(sse_g, wsum[0] + wsum[1] + wsum[2] + wsum[3]);

    for (int i = tid; i < K; i += 256) {
        int h = hist[i];
        if (h) atomicAdd(&counts[i], h);
    }
}

// ---------------------------------------------------------------------------
// Scalars: vq_loss = 1.25 * SSE / NELEM; entropy in bits from counts.
__global__ void k_final(const double* __restrict__ sse_g, const int* __restrict__ counts,
                        float* __restrict__ out_scalars)
{
    __shared__ double part[8];
    const int t = threadIdx.x;  // 512 threads
    int c = counts[t];
    double p = (double)c / (double)NVEC;
    double h = (c > 0) ? (-p * log2(p)) : 0.0;
    #pragma unroll
    for (int off = 32; off; off >>= 1) h += __shfl_down(h, off, 64);
    if ((t & 63) == 0) part[t >> 6] = h;
    __syncthreads();
    if (t == 0) {
        double H = 0.0;
        #pragma unroll
        for (int i = 0; i < 8; ++i) H += part[i];
        out_scalars[0] = (float)(1.25 * (*sse_g) / (double)NELEM);
        out_scalars[1] = (float)H;
    }
}

// ---------------------------------------------------------------------------
extern "C" void kernel_launch(void* const* d_in, const int* in_sizes, int n_in,
                              void* d_out, int out_size, void* d_ws, size_t ws_size,
                              hipStream_t stream)
{
    const float* x  = (const float*)d_in[0];
    const float* cb = (const float*)d_in[1];

    char* ws = (char*)d_ws;
    double* sse    = (double*)(ws + OFF_SSE);
    int*    counts = (int*)   (ws + OFF_COUNTS);
    float*  S2     = (float*) (ws + OFF_S2);
    int*    idx    = (int*)   (ws + OFF_IDX);

    float* outq   = (float*)d_out;
    float* outidx = outq + NELEM;
    float* outsc  = outidx + NVEC;

    // zero sse + counts (ws is poisoned 0xAA before every launch)
    hipMemsetAsync(d_ws, 0, OFF_S2, stream);

    k_prep  <<<1, 512, 0, stream>>>(cb, S2);
    k_scores<<<NVEC / 256, 256, 0, stream>>>(x, cb, S2, idx);
    k_out   <<<NVEC / 256, 256, 0, stream>>>(x, cb, idx, outq, outidx, sse, counts);
    k_final <<<1, 512, 0, stream>>>(sse, counts, outsc);
}

// Round 4
// 830.454 us; speedup vs baseline: 1.0583x; 1.0583x over previous
//
#include <hip/hip_runtime.h>

// Problem constants
constexpr int K    = 512;                 // codebook size
constexpr int CDIM = 64;                  // vector dim
constexpr int NVEC = 8 * 16 * 64 * 64;    // 524288 vectors
constexpr long long NELEM = (long long)NVEC * CDIM; // 33554432

// ws layout (bytes):
//   0    : double sse
//   8    : pad
//   16   : int    counts[512]   (ends 2064)
//   2064 : float  S2[512]
constexpr size_t OFF_SSE    = 0;
constexpr size_t OFF_COUNTS = 16;
constexpr size_t OFF_S2     = 16 + 4 * (size_t)K;

// ---------------------------------------------------------------------------
// S2[k] = np.sum(cb[k]*cb[k]) with numpy pairwise semantics (squares rounded
// first, 8 strided accumulators, fixed combine tree).
__global__ void k_prep(const float* __restrict__ cb, float* __restrict__ S2)
{
#pragma clang fp contract(off)
    int k = threadIdx.x;  // 512 threads, 1 block
    const float* e = cb + (k << 6);
    float sq[CDIM];
    #pragma unroll
    for (int c = 0; c < CDIM; ++c) {
        float v = e[c];
        sq[c] = v * v;                     // rounded square, NO fma
    }
    float r[8];
    #pragma unroll
    for (int j = 0; j < 8; ++j) r[j] = sq[j];
    #pragma unroll
    for (int i = 8; i < CDIM; i += 8)
        #pragma unroll
        for (int j = 0; j < 8; ++j) r[j] += sq[i + j];
    S2[k] = ((r[0] + r[1]) + (r[2] + r[3])) + ((r[4] + r[5]) + (r[6] + r[7]));
}

// ---------------------------------------------------------------------------
// Fused: bit-exact numpy-fp32 argmin + all outputs.
//   D[n,k] = (S1[n] - 2*G[n,k]) + S2[k],  G = sequential-fma dot (BLAS order),
//   idx = first minimum; then gather/quantize/SSE/histogram in the epilogue.
__global__ __launch_bounds__(256, 2)
void k_main(const float* __restrict__ x, const float* __restrict__ cb,
            const float* __restrict__ S2g, float* __restrict__ outq,
            float* __restrict__ outidx, double* __restrict__ sse_g,
            int* __restrict__ counts)
{
#pragma clang fp contract(off)
    __shared__ int    hist[K];
    __shared__ double wsum[4];
    const int tid = threadIdx.x;
    for (int i = tid; i < K; i += 256) hist[i] = 0;
    __syncthreads();

    const int n  = blockIdx.x * 256 + tid;
    const int bt = n >> 12;           // (b*16+t)
    const int hw = n & 4095;          // h*64+w
    const size_t base = ((size_t)bt << 18) + (size_t)hw;
    const float* xv = x + base;

    // Load the 64-element vector, then PIN it in VGPRs: the empty asm makes
    // each value opaque so the compiler cannot rematerialize the load inside
    // the k-loop (round-2 failure mode: VGPR=40, f reloaded per fma from L1).
    float f[CDIM];
    #pragma unroll
    for (int c = 0; c < CDIM; ++c) f[c] = xv[(size_t)c << 12];
    #pragma unroll
    for (int c = 0; c < CDIM; ++c) asm volatile("" : "+v"(f[c]));

    // S1 = np pairwise sum of f*f (squares rounded first)
    float r[8];
    #pragma unroll
    for (int j = 0; j < 8; ++j) r[j] = f[j] * f[j];
    #pragma unroll
    for (int i = 8; i < CDIM; i += 8)
        #pragma unroll
        for (int j = 0; j < 8; ++j) r[j] += f[i + j] * f[i + j];
    const float S1 = ((r[0] + r[1]) + (r[2] + r[3])) + ((r[4] + r[5]) + (r[6] + r[7]));

    float best  = 3.4e38f;
    int   bestk = 0;

    for (int k = 0; k < K; k += 4) {
        const float4* e0 = (const float4*)(cb + ((k + 0) << 6));
        const float4* e1 = (const float4*)(cb + ((k + 1) << 6));
        const float4* e2 = (const float4*)(cb + ((k + 2) << 6));
        const float4* e3 = (const float4*)(cb + ((k + 3) << 6));
        float g0 = 0.f, g1 = 0.f, g2 = 0.f, g3 = 0.f;
        #pragma unroll
        for (int c4 = 0; c4 < 16; ++c4) {
            const int c = c4 * 4;
            float4 a = e0[c4];
            g0 = fmaf(f[c + 0], a.x, g0); g0 = fmaf(f[c + 1], a.y, g0);
            g0 = fmaf(f[c + 2], a.z, g0); g0 = fmaf(f[c + 3], a.w, g0);
            float4 b = e1[c4];
            g1 = fmaf(f[c + 0], b.x, g1); g1 = fmaf(f[c + 1], b.y, g1);
            g1 = fmaf(f[c + 2], b.z, g1); g1 = fmaf(f[c + 3], b.w, g1);
            float4 cc = e2[c4];
            g2 = fmaf(f[c + 0], cc.x, g2); g2 = fmaf(f[c + 1], cc.y, g2);
            g2 = fmaf(f[c + 2], cc.z, g2); g2 = fmaf(f[c + 3], cc.w, g2);
            float4 d = e3[c4];
            g3 = fmaf(f[c + 0], d.x, g3); g3 = fmaf(f[c + 1], d.y, g3);
            g3 = fmaf(f[c + 2], d.z, g3); g3 = fmaf(f[c + 3], d.w, g3);
        }
        // D = (S1 - 2*G) + S2   (2*G exact; adds round at magnitude ~64,
        // exactly like numpy's broadcast expression)
        const float d0 = (S1 - 2.f * g0) + S2g[k + 0];
        const float d1 = (S1 - 2.f * g1) + S2g[k + 1];
        const float d2 = (S1 - 2.f * g2) + S2g[k + 2];
        const float d3 = (S1 - 2.f * g3) + S2g[k + 3];
        // first-minimum selection, ascending k
        if (d0 < best) { best = d0; bestk = k + 0; }
        if (d1 < best) { best = d1; bestk = k + 1; }
        if (d2 < best) { best = d2; bestk = k + 2; }
        if (d3 < best) { best = d3; bestk = k + 3; }
    }

    // ---------------- epilogue (was k_out) ----------------
    atomicAdd(&hist[bestk], 1);
    outidx[n] = (float)bestk;

    const float4* e4 = (const float4*)(cb + (bestk << 6));
    double acc = 0.0;
    #pragma unroll
    for (int c4 = 0; c4 < 16; ++c4) {
        float4 e = e4[c4];
        const int c = c4 * 4;
        float d0 = e.x - f[c + 0];
        float d1 = e.y - f[c + 1];
        float d2 = e.z - f[c + 2];
        float d3 = e.w - f[c + 3];
        outq[base + ((size_t)(c + 0) << 12)] = e.x;
        outq[base + ((size_t)(c + 1) << 12)] = e.y;
        outq[base + ((size_t)(c + 2) << 12)] = e.z;
        outq[base + ((size_t)(c + 3) << 12)] = e.w;
        acc += (double)d0 * d0 + (double)d1 * d1 + (double)d2 * d2 + (double)d3 * d3;
    }

    double v = acc;
    #pragma unroll
    for (int off = 32; off; off >>= 1) v += __shfl_down(v, off, 64);
    if ((tid & 63) == 0) wsum[tid >> 6] = v;
    __syncthreads();
    if (tid == 0) atomicAdd(sse_g, wsum[0] + wsum[1] + wsum[2] + wsum[3]);

    for (int i = tid; i < K; i += 256) {
        int h = hist[i];
        if (h) atomicAdd(&counts[i], h);
    }
}

// ---------------------------------------------------------------------------
// Scalars: vq_loss = 1.25 * SSE / NELEM; entropy in bits from counts.
__global__ void k_final(const double* __restrict__ sse_g, const int* __restrict__ counts,
                        float* __restrict__ out_scalars)
{
    __shared__ double part[8];
    const int t = threadIdx.x;  // 512 threads
    int c = counts[t];
    double p = (double)c / (double)NVEC;
    double h = (c > 0) ? (-p * log2(p)) : 0.0;
    #pragma unroll
    for (int off = 32; off; off >>= 1) h += __shfl_down(h, off, 64);
    if ((t & 63) == 0) part[t >> 6] = h;
    __syncthreads();
    if (t == 0) {
        double H = 0.0;
        #pragma unroll
        for (int i = 0; i < 8; ++i) H += part[i];
        out_scalars[0] = (float)(1.25 * (*sse_g) / (double)NELEM);
        out_scalars[1] = (float)H;
    }
}

// ---------------------------------------------------------------------------
extern "C" void kernel_launch(void* const* d_in, const int* in_sizes, int n_in,
                              void* d_out, int out_size, void* d_ws, size_t ws_size,
                              hipStream_t stream)
{
    const float* x  = (const float*)d_in[0];
    const float* cb = (const float*)d_in[1];

    char* ws = (char*)d_ws;
    double* sse    = (double*)(ws + OFF_SSE);
    int*    counts = (int*)   (ws + OFF_COUNTS);
    float*  S2     = (float*) (ws + OFF_S2);

    float* outq   = (float*)d_out;
    float* outidx = outq + NELEM;
    float* outsc  = outidx + NVEC;

    // zero sse + counts (ws is poisoned 0xAA before every launch)
    hipMemsetAsync(d_ws, 0, OFF_S2, stream);

    k_prep <<<1, 512, 0, stream>>>(cb, S2);
    k_main <<<NVEC / 256, 256, 0, stream>>>(x, cb, S2, outq, outidx, sse, counts);
    k_final<<<1, 512, 0, stream>>>(sse, counts, outsc);
}